// Round 6
// baseline (4523.867 us; speedup 1.0000x reference)
//
#include <hip/hip_runtime.h>

// LSTM char-RNN scan: B=512, SEQ=1024, UNITS=256, NUM_CHARS=128. fp32 in/out.
// Round 20: break the 2-wave/SIMD phase-lock -- 16 waves, 1 unit-block/wave.
//   Post-mortem r17-r19: three flat rounds at ~1890 us. Accounting: pipe
//   busy ~2100 cy/step (47% active MfmaUtil), tail ~2300 cy with the pipe
//   IDLE. The tail is latency-bound (chain deps, LDS h round-trip, barrier)
//   and with only 2 lockstep waves/SIMD there is no TLP to hide it.
//   Restructure at CONSTANT pipe work:
//   - THREADS=1024, 16 waves, 4 waves/SIMD. Wave wv owns unit block wv
//     (16 units) x all 4 gates: WR[4][8] = 128 AGPR + acc 16 = 144 <= 256.
//   - No LDS W-tiles at all (lw reads deleted; LDS ~19 KB).
//   - 1 cell/lane update (chain VALU halves), 1 Wxp gather/lane.
//   - kt=0 peeled with persistent zero-C frag (MFMA D!=C legal): no
//     per-step acc zero-init.
//   - MFMA/SIMD/step unchanged: 4 waves x 32 = 128.
// Numerics frozen: W_h bf16 RNE (log2e pre-scaled), h bf16 RNE, c/gates
// fp32, rcp+exp2 gates (absmax 4.8828e-4).

#define U       256
#define SEQ     1024
#define NC      128
#define GDIM    1024
#define BCR     4          // batch rows per WG (at M-rows 0,4,8,12)
#define THREADS 1024       // 16 waves

typedef short bf16x8 __attribute__((ext_vector_type(8)));
typedef float f32x4  __attribute__((ext_vector_type(4)));

#define WP_OFF   0                        // 512 KB packed W_h
#define WXP_OFF  (512*1024)               // 512 KB packed Wx+bias
#define WS_NEED  (1024*1024)

#define L2E   1.4426950408889634f
#define L2E2  2.8853900817779268f

#if __has_builtin(__builtin_amdgcn_exp2f)
#define EXP2(x) __builtin_amdgcn_exp2f(x)
#else
#define EXP2(x) __expf((x) * 0.6931471805599453f)
#endif
#if __has_builtin(__builtin_amdgcn_rcpf)
#define RCPF(x) __builtin_amdgcn_rcpf(x)
#else
#define RCPF(x) (1.0f / (x))
#endif

__device__ __forceinline__ float sig_(float x)  { return 1.0f / (1.0f + __expf(-x)); }
__device__ __forceinline__ float tanh_(float x) { return 1.0f - 2.0f / (__expf(2.0f * x) + 1.0f); }
__device__ __forceinline__ unsigned rne16(float f) {
    union { float f; unsigned u; } v; v.f = f;
    return (v.u + 0x7FFFu + ((v.u >> 16) & 1u)) >> 16;
}
__device__ __forceinline__ float u2f(unsigned u) {
    union { unsigned u; float f; } v; v.u = u; return v.f;
}

// ---- pack W_h into MFMA B-frag order (validated rounds 5-19) ----
// Wp[(nt*8+kt)*64 + lane]: col = nt*16+(lane&15); k = kt*32+(lane>>4)*8 + j,
// dword d packs (k=2d lo, k=2d+1 hi).  Columns pre-scaled: j-gate (cols
// 256..511) x 2log2e, others x log2e (exp2-form gates).
__global__ __launch_bounds__(256)
void pack_wh(const float* __restrict__ Wh, uint4* __restrict__ Wp) {
    int i    = blockIdx.x * 256 + threadIdx.x;   // [0, 32768)
    int lane = i & 63;
    int kt   = (i >> 6) & 7;
    int nt   = i >> 9;
    int col  = nt * 16 + (lane & 15);
    int k0   = kt * 32 + ((lane >> 4) * 8);
    const float s = (col >= 256 && col < 512) ? L2E2 : L2E;
    const float* base = Wh + (size_t)k0 * GDIM + col;
    unsigned p0 = rne16(base[0 * GDIM] * s) | (rne16(base[1 * GDIM] * s) << 16);
    unsigned p1 = rne16(base[2 * GDIM] * s) | (rne16(base[3 * GDIM] * s) << 16);
    unsigned p2 = rne16(base[4 * GDIM] * s) | (rne16(base[5 * GDIM] * s) << 16);
    unsigned p3 = rne16(base[6 * GDIM] * s) | (rne16(base[7 * GDIM] * s) << 16);
    Wp[i] = make_uint4(p0, p1, p2, p3);
}

// ---- pack Wx + bias (+forget_bias) into float4 per (x, unit), scaled ----
__global__ __launch_bounds__(256)
void pack_wx(const float* __restrict__ Wx, const float* __restrict__ bias,
             float4* __restrict__ Wxp) {
    int i = blockIdx.x * 256 + threadIdx.x;      // [0, 32768)
    int x = i >> 8, u = i & 255;
    const float* r = Wx + (size_t)x * GDIM;
    Wxp[i] = make_float4((r[u]       + bias[u])              * L2E,
                         (r[256 + u] + bias[256 + u])        * L2E2,
                         (r[512 + u] + bias[512 + u] + 1.0f) * L2E,  // forget_bias
                         (r[768 + u] + bias[768 + u])        * L2E);
}

__global__ __launch_bounds__(THREADS, 1)
void lstm_w128(const int* __restrict__ tokens,
               const uint4* __restrict__ Wp,     // packed W_h (ws)
               const float4* __restrict__ Wxp,   // packed Wx+b (ws)
               const float* __restrict__ Wd,     // [256,128]
               const float* __restrict__ bd,     // [128]
               float* __restrict__ out)          // [512,128]
{
    __shared__ __align__(16) short AH[2][8][64][8]; // 16 KB h bf16, double-buffered
    __shared__ int   tokw[64][4];                   // 1 KB 64-step token window

    const int tid  = threadIdx.x;
    const int wv   = tid >> 6;        // wave 0..15
    const int lane = tid & 63;
    const int m    = lane & 15;
    const int quad = lane >> 4;
    const int r0   = blockIdx.x * BCR;

    // wave wv owns unit block wv (16 units), all 4 gates in AGPR:
    // nt tiles {wv (i), 16+wv (j), 32+wv (f), 48+wv (o)}.
    bf16x8 WR[4][8];                  // 128 AGPRs
    #pragma unroll
    for (int g = 0; g < 4; ++g)
        #pragma unroll
        for (int kt = 0; kt < 8; ++kt) {
            union { uint4 u; bf16x8 v; } c;
            c.u = Wp[((size_t)((g * 16 + wv) * 8 + kt)) * 64 + lane];
            WR[g][kt] = c.v;
        }
    for (int i = tid; i < 4096; i += THREADS)    // zero both A planes (as ints)
        ((int*)AH)[i] = 0;

    // update-phase constants: EVERY lane updates batch row `quad` (M-row
    // 4*quad, acc[.][0]) of unit u0 = wv*16+m.
    float cst0 = 0.f;
    const int u0 = wv * 16 + m;
    const int kt0 = u0 >> 5, qa0 = (u0 >> 3) & 3, j0 = u0 & 7;
    const int myrow = 4 * quad;       // M-row holding this lane's batch row

    const f32x4 zc = (f32x4){0.f, 0.f, 0.f, 0.f};   // persistent zero-C frag
    int xq = 0;                       // this step's token for batch row `quad`

    __syncthreads();

    for (int t = 0; t < SEQ; ++t) {
        if ((t & 63) == 0) {           // refresh token window (64 x 4 ints)
            if (tid < 256)
                tokw[tid >> 2][tid & 3] =
                    tokens[(size_t)(r0 + (tid & 3)) * SEQ + t + (tid >> 2)];
            __syncthreads();
            xq = tokw[0][quad];
        }
        const int p = t & 1;

        // ---- Wxp gather first (longest latency, used only in the chain) ----
        const float4 wxa = Wxp[(size_t)xq * 256 + u0];

        // ---- ah fragments: read ONCE, reused by all 32 MFMAs ----
        bf16x8 ah[8];
        #pragma unroll
        for (int kt = 0; kt < 8; ++kt)
            ah[kt] = *(const bf16x8*)&AH[p][kt][lane][0];

        // ---- MFMA: kt=0 peeled with zero-C (no acc init) ----
        // acc: [0]=i [1]=j [2]=f [3]=o
        f32x4 acc[4];
        acc[0] = __builtin_amdgcn_mfma_f32_16x16x32_bf16(ah[0], WR[0][0], zc, 0, 0, 0);
        acc[1] = __builtin_amdgcn_mfma_f32_16x16x32_bf16(ah[0], WR[1][0], zc, 0, 0, 0);
        acc[2] = __builtin_amdgcn_mfma_f32_16x16x32_bf16(ah[0], WR[2][0], zc, 0, 0, 0);
        #pragma unroll
        for (int kt = 1; kt < 8; ++kt) {
            acc[0] = __builtin_amdgcn_mfma_f32_16x16x32_bf16(ah[kt], WR[0][kt], acc[0], 0, 0, 0);
            acc[1] = __builtin_amdgcn_mfma_f32_16x16x32_bf16(ah[kt], WR[1][kt], acc[1], 0, 0, 0);
            acc[2] = __builtin_amdgcn_mfma_f32_16x16x32_bf16(ah[kt], WR[2][kt], acc[2], 0, 0, 0);
        }
        // o-gate last: its 8 MFMAs drain while the c-chain (i,j,f) runs
        acc[3] = __builtin_amdgcn_mfma_f32_16x16x32_bf16(ah[0], WR[3][0], zc, 0, 0, 0);
        #pragma unroll
        for (int kt = 1; kt < 8; ++kt)
            acc[3] = __builtin_amdgcn_mfma_f32_16x16x32_bf16(ah[kt], WR[3][kt], acc[3], 0, 0, 0);

        // ---- c-chain: needs only i,j,f. exp2-form gates. ----
        float gi = acc[0][0] + wxa.x;            // x log2e pre-scaled
        float gj = acc[1][0] + wxa.y;            // x 2log2e pre-scaled
        float gf = acc[2][0] + wxa.z;            // forget_bias folded
        float si = RCPF(1.0f + EXP2(-gi));
        float tj = fmaf(-2.0f, RCPF(EXP2(gj) + 1.0f), 1.0f);
        float sf = RCPF(1.0f + EXP2(-gf));
        float c  = fmaf(cst0, sf, si * tj);
        cst0 = c;
        float th = fmaf(-2.0f, RCPF(EXP2(c * L2E2) + 1.0f), 1.0f);

        // ---- o-gate tail (first read of acc[3]) + h write ----
        float so = RCPF(1.0f + EXP2(-(acc[3][0] + wxa.w)));
        AH[p ^ 1][kt0][qa0 * 16 + myrow][j0] = (short)rne16(th * so);

        // prefetch next step's token (window-interior only)
        if (((t + 1) & 63) != 0)
            xq = tokw[(t + 1) & 63][quad];

        __syncthreads();       // single barrier: plane p^1 now visible
    }

    // ---- final dense (h is bf16 in plane 0; 4 rows x 128 cols) ----
    // batch row r lives at M-row 4r.
    for (int o = tid; o < BCR * NC; o += THREADS) {
        const int r = o >> 7;
        const int n = o & (NC - 1);
        float sum = bd[n];
        #pragma unroll 4
        for (int k = 0; k < U; ++k) {
            float hk = u2f(((unsigned)(unsigned short)
                            AH[0][k >> 5][((k >> 3) & 3) * 16 + 4 * r][k & 7]) << 16);
            sum = fmaf(hk, Wd[k * NC + n], sum);
        }
        out[(size_t)(r0 + r) * NC + n] = sum;
    }
}

// ================= fallback: round-5 streaming kernel (proven 7.6 ms) =========
__global__ __launch_bounds__(256)
void pack_kq(const float* __restrict__ Wh, uint4* __restrict__ Whb) {
    int idx = blockIdx.x * 256 + threadIdx.x;
    int kq  = idx >> 10;
    int c   = idx & 1023;
    const float* base = Wh + (size_t)(kq * 8) * GDIM + c;
    unsigned p0 = rne16(base[0 * GDIM]) | (rne16(base[1 * GDIM]) << 16);
    unsigned p1 = rne16(base[2 * GDIM]) | (rne16(base[3 * GDIM]) << 16);
    unsigned p2 = rne16(base[4 * GDIM]) | (rne16(base[5 * GDIM]) << 16);
    unsigned p3 = rne16(base[6 * GDIM]) | (rne16(base[7 * GDIM]) << 16);
    Whb[idx] = make_uint4(p0, p1, p2, p3);
}

__global__ __launch_bounds__(1024, 4)
void lstm_stream(const int* __restrict__ tokens, const float* __restrict__ Wx,
                 const uint4* __restrict__ Whb, const float* __restrict__ bias,
                 const float* __restrict__ Wd, const float* __restrict__ bd,
                 float* __restrict__ out)
{
    __shared__ float h32[2][U];
    __shared__ float G2[GDIM][2];
    __shared__ int   tok[2][SEQ];
    const int tid = threadIdx.x;
    const int r0  = blockIdx.x * 2;
    for (int i = tid; i < 2 * SEQ; i += 1024)
        ((int*)tok)[i] = tokens[r0 * SEQ + i];
    if (tid < 2 * U) ((float*)h32)[tid] = 0.0f;
    const float b_c = bias[tid];
    float c_state = 0.0f;
    const int ur = tid >> 8, uu = tid & 255;
    __syncthreads();
    const uint4* wp = Whb + tid;
    for (int t = 0; t < SEQ; ++t) {
        const int x0 = tok[0][t], x1 = tok[1][t];
        float a0e = Wx[x0 * GDIM + tid] + b_c;
        float a1e = Wx[x1 * GDIM + tid] + b_c;
        float a0o = 0.f, a1o = 0.f;
        #pragma unroll 4
        for (int kq = 0; kq < 32; ++kq) {
            float4 h0a = *(const float4*)&h32[0][kq * 8];
            float4 h0b = *(const float4*)&h32[0][kq * 8 + 4];
            float4 h1a = *(const float4*)&h32[1][kq * 8];
            float4 h1b = *(const float4*)&h32[1][kq * 8 + 4];
            uint4 wv2 = wp[kq << 10];
            float we0 = u2f(wv2.x << 16), wo0 = u2f(wv2.x & 0xffff0000u);
            float we1 = u2f(wv2.y << 16), wo1 = u2f(wv2.y & 0xffff0000u);
            float we2 = u2f(wv2.z << 16), wo2 = u2f(wv2.z & 0xffff0000u);
            float we3 = u2f(wv2.w << 16), wo3 = u2f(wv2.w & 0xffff0000u);
            a0e = fmaf(h0a.x, we0, a0e); a0o = fmaf(h0a.y, wo0, a0o);
            a1e = fmaf(h1a.x, we0, a1e); a1o = fmaf(h1a.y, wo0, a1o);
            a0e = fmaf(h0a.z, we1, a0e); a0o = fmaf(h0a.w, wo1, a0o);
            a1e = fmaf(h1a.z, we1, a1e); a1o = fmaf(h1a.w, wo1, a1o);
            a0e = fmaf(h0b.x, we2, a0e); a0o = fmaf(h0b.y, wo2, a0o);
            a1e = fmaf(h1b.x, we2, a1e); a1o = fmaf(h1b.y, wo2, a1o);
            a0e = fmaf(h0b.z, we3, a0e); a0o = fmaf(h0b.w, wo3, a0o);
            a1e = fmaf(h1b.z, we3, a1e); a1o = fmaf(h1b.w, wo3, a1o);
        }
        *(float2*)&G2[tid][0] = make_float2(a0e + a0o, a1e + a1o);
        __syncthreads();
        if (tid < 2 * U) {
            float gi = G2[uu][ur], gj = G2[U + uu][ur];
            float gf = G2[2 * U + uu][ur], go = G2[3 * U + uu][ur];
            c_state = c_state * sig_(gf + 1.0f) + sig_(gi) * tanh_(gj);
            h32[ur][uu] = tanh_(c_state) * sig_(go);
        }
        __syncthreads();
    }
    if (tid < 2 * NC) {
        const int r = tid >> 7, n = tid & (NC - 1);
        float sum = bd[n];
        #pragma unroll 4
        for (int k = 0; k < U; ++k)
            sum = fmaf(h32[r][k], Wd[k * NC + n], sum);
        out[(r0 + r) * NC + n] = sum;
    }
}

extern "C" void kernel_launch(void* const* d_in, const int* in_sizes, int n_in,
                              void* d_out, int out_size, void* d_ws, size_t ws_size,
                              hipStream_t stream) {
    const int*   tokens = (const int*)d_in[0];
    const float* Wx     = (const float*)d_in[1];
    const float* Wh     = (const float*)d_in[2];
    const float* bias   = (const float*)d_in[3];
    const float* Wd     = (const float*)d_in[4];
    const float* bd     = (const float*)d_in[5];
    float*       out    = (float*)d_out;

    if (ws_size >= (size_t)WS_NEED) {
        uint4*  Wp  = (uint4*)((char*)d_ws + WP_OFF);
        float4* Wxp = (float4*)((char*)d_ws + WXP_OFF);
        pack_wh<<<128, 256, 0, stream>>>(Wh, Wp);
        pack_wx<<<128, 256, 0, stream>>>(Wx, bias, Wxp);
        lstm_w128<<<512 / BCR, THREADS, 0, stream>>>(tokens, Wp, Wxp, Wd, bd, out);
    } else {
        uint4* Whb = (uint4*)d_ws;
        pack_kq<<<128, 256, 0, stream>>>(Wh, Whb);
        lstm_stream<<<256, 1024, 0, stream>>>(tokens, Wx, Whb, bias, Wd, bd, out);
    }
}

// Round 7
// 1416.976 us; speedup vs baseline: 3.1926x; 3.1926x over previous
//
#include <hip/hip_runtime.h>

// LSTM char-RNN scan: B=512, SEQ=1024, UNITS=256, NUM_CHARS=128. fp32 in/out.
// Round 21: BCR=2 -> 256 CUs, 1 cell/lane (quad-split row x unit-block).
//   Model fit r15-r19: step = 2480 (pipe, invariant: 512 MFMA/WG/step for
//   any BCR<=16) + ~1000 x cells/lane (latency-bound serialized chains:
//   gather + trans chain per cell) + ~300 fixed. r20 (16-wave) spilled
//   (VGPR 64, WRITE 4x) AND serialized acc streams -- reverted.
//   This round: halve BCR at constant per-CU pipe work:
//   - 256 WGs on 256 CUs (2x CUs vs r19).
//   - quad-split cell map: rsel=quad&1 picks batch row (M-rows 0/4, h
//     DUPLICATED at 8/12 so every quad's acc[.][0] is a real row);
//     bsel=quad>>1 picks unit block (A: acc[0,2,4,6] / B: acc[1,3,5,7]).
//     -> exactly 1 cell per lane, all 64 lanes useful, 1 Wxp gather/lane,
//     2 ds_write_b16 (both M-row copies).
//   - skeleton = r19 (proven 1887): 8 waves, WR 6 AGPR tiles + 2 LDS
//     tiles VGPR-hoisted per step, pass A (i,j,f) -> pass B (o) -> chain,
//     single barrier, double-buffered AH.
// Numerics frozen: W_h bf16 RNE (log2e pre-scaled), h bf16 RNE, c/gates
// fp32, rcp+exp2 gates (absmax 4.8828e-4).

#define U       256
#define SEQ     1024
#define NC      128
#define GDIM    1024
#define BCR     2          // batch rows per WG (M-rows 0,4; dup at 8,12)
#define THREADS 512        // 8 waves

typedef short bf16x8 __attribute__((ext_vector_type(8)));
typedef float f32x4  __attribute__((ext_vector_type(4)));

#define WP_OFF   0                        // 512 KB packed W_h
#define WXP_OFF  (512*1024)               // 512 KB packed Wx+bias
#define WS_NEED  (1024*1024)

#define L2E   1.4426950408889634f
#define L2E2  2.8853900817779268f

#if __has_builtin(__builtin_amdgcn_exp2f)
#define EXP2(x) __builtin_amdgcn_exp2f(x)
#else
#define EXP2(x) __expf((x) * 0.6931471805599453f)
#endif
#if __has_builtin(__builtin_amdgcn_rcpf)
#define RCPF(x) __builtin_amdgcn_rcpf(x)
#else
#define RCPF(x) (1.0f / (x))
#endif

__device__ __forceinline__ float sig_(float x)  { return 1.0f / (1.0f + __expf(-x)); }
__device__ __forceinline__ float tanh_(float x) { return 1.0f - 2.0f / (__expf(2.0f * x) + 1.0f); }
__device__ __forceinline__ unsigned rne16(float f) {
    union { float f; unsigned u; } v; v.f = f;
    return (v.u + 0x7FFFu + ((v.u >> 16) & 1u)) >> 16;
}
__device__ __forceinline__ float u2f(unsigned u) {
    union { unsigned u; float f; } v; v.u = u; return v.f;
}

// ---- pack W_h into MFMA B-frag order (validated rounds 5-20) ----
// Wp[(nt*8+kt)*64 + lane]: col = nt*16+(lane&15); k = kt*32+(lane>>4)*8 + j,
// dword d packs (k=2d lo, k=2d+1 hi).  Columns pre-scaled: j-gate (cols
// 256..511) x 2log2e, others x log2e (exp2-form gates).
__global__ __launch_bounds__(256)
void pack_wh(const float* __restrict__ Wh, uint4* __restrict__ Wp) {
    int i    = blockIdx.x * 256 + threadIdx.x;   // [0, 32768)
    int lane = i & 63;
    int kt   = (i >> 6) & 7;
    int nt   = i >> 9;
    int col  = nt * 16 + (lane & 15);
    int k0   = kt * 32 + ((lane >> 4) * 8);
    const float s = (col >= 256 && col < 512) ? L2E2 : L2E;
    const float* base = Wh + (size_t)k0 * GDIM + col;
    unsigned p0 = rne16(base[0 * GDIM] * s) | (rne16(base[1 * GDIM] * s) << 16);
    unsigned p1 = rne16(base[2 * GDIM] * s) | (rne16(base[3 * GDIM] * s) << 16);
    unsigned p2 = rne16(base[4 * GDIM] * s) | (rne16(base[5 * GDIM] * s) << 16);
    unsigned p3 = rne16(base[6 * GDIM] * s) | (rne16(base[7 * GDIM] * s) << 16);
    Wp[i] = make_uint4(p0, p1, p2, p3);
}

// ---- pack Wx + bias (+forget_bias) into float4 per (x, unit), scaled ----
__global__ __launch_bounds__(256)
void pack_wx(const float* __restrict__ Wx, const float* __restrict__ bias,
             float4* __restrict__ Wxp) {
    int i = blockIdx.x * 256 + threadIdx.x;      // [0, 32768)
    int x = i >> 8, u = i & 255;
    const float* r = Wx + (size_t)x * GDIM;
    Wxp[i] = make_float4((r[u]       + bias[u])              * L2E,
                         (r[256 + u] + bias[256 + u])        * L2E2,
                         (r[512 + u] + bias[512 + u] + 1.0f) * L2E,  // forget_bias
                         (r[768 + u] + bias[768 + u])        * L2E);
}

__global__ __launch_bounds__(THREADS, 2)
void lstm_w256(const int* __restrict__ tokens,
               const uint4* __restrict__ Wp,     // packed W_h (ws)
               const float4* __restrict__ Wxp,   // packed Wx+b (ws)
               const float* __restrict__ Wd,     // [256,128]
               const float* __restrict__ bd,     // [128]
               float* __restrict__ out)          // [512,128]
{
    __shared__ uint4 LW[16][8][64];              // 128 KB  o-gate W in LDS
    __shared__ __align__(16) short AH[2][8][64][8]; // 16 KB h bf16, double-buffered
    __shared__ int   tokw[64][2];                // 0.5 KB 64-step token window

    const int tid  = threadIdx.x;
    const int wv   = tid >> 6;        // wave 0..7
    const int lane = tid & 63;
    const int m    = lane & 15;
    const int quad = lane >> 4;
    const int r0   = blockIdx.x * BCR;

    // wave wv owns unit blocks {wv, 8+wv} (32 units), all 4 gates:
    // REG tiles (i,j,f both blocks, AGPR): nt {wv..40+wv step 8}.
    // LDS tiles (o gates):                 nt {48+wv, 56+wv}.
    bf16x8 WR[6][8];                  // 192 AGPRs
    #pragma unroll
    for (int jj = 0; jj < 6; ++jj)
        #pragma unroll
        for (int kt = 0; kt < 8; ++kt) {
            union { uint4 u; bf16x8 v; } c;
            c.u = Wp[((size_t)((wv + 8 * jj) * 8 + kt)) * 64 + lane];
            WR[jj][kt] = c.v;
        }
    const int slA = 2 * wv;
    #pragma unroll
    for (int kt = 0; kt < 8; ++kt) {
        LW[slA][kt][lane]     = Wp[((size_t)((48 + wv) * 8 + kt)) * 64 + lane];
        LW[slA + 1][kt][lane] = Wp[((size_t)((56 + wv) * 8 + kt)) * 64 + lane];
    }
    for (int i = tid; i < 4096; i += THREADS)    // zero both A planes (as ints)
        ((int*)AH)[i] = 0;

    // cell map: rsel = batch row (M-row 4*rsel, dup at +8); bsel = unit blk.
    const int rsel = quad & 1;
    const int bsel = quad >> 1;
    const int u0 = wv * 16 + m;
    const int u1 = (8 + wv) * 16 + m;
    const int ub = bsel ? u1 : u0;               // unit this lane updates
    const int ktu = ub >> 5, qau = (ub >> 3) & 3, ju = ub & 7;
    const int mrow = 4 * rsel;                   // primary M-row of my batch row

    float cst0 = 0.f;
    int xq = 0;                       // this step's token for batch row rsel

    __syncthreads();

    for (int t = 0; t < SEQ; ++t) {
        if ((t & 63) == 0) {           // refresh token window (64 x 2 ints)
            if (tid < 128)
                tokw[tid >> 1][tid & 1] =
                    tokens[(size_t)(r0 + (tid & 1)) * SEQ + t + (tid >> 1)];
            __syncthreads();
            xq = tokw[0][rsel];
        }
        const int p = t & 1;

        // ---- issue order: VMEM gather first (longest latency) ----
        const float4 wx = Wxp[(size_t)xq * 256 + ub];

        // ---- ah fragments: read ONCE (gates pass A via lgkmcnt) ----
        bf16x8 ah[8];
        #pragma unroll
        for (int kt = 0; kt < 8; ++kt)
            ah[kt] = *(const bf16x8*)&AH[p][kt][lane][0];

        // ---- lw o-gate tiles: issued now, consumed only in pass B ->
        // the 16 reads drain UNDER pass A's MFMA issue ----
        bf16x8 lw0[8], lw1[8];
        #pragma unroll
        for (int kt = 0; kt < 8; ++kt) {
            union { uint4 u; bf16x8 v; } c0, c1;
            c0.u = LW[slA][kt][lane];
            c1.u = LW[slA + 1][kt][lane];
            lw0[kt] = c0.v;
            lw1[kt] = c1.v;
        }

        f32x4 acc[8];
        #pragma unroll
        for (int j = 0; j < 8; ++j) acc[j] = (f32x4){0.f, 0.f, 0.f, 0.f};

        // ---- pass A: i,j,f gates (48 MFMA, AGPR B-operands) ----
        #pragma unroll
        for (int kt = 0; kt < 8; ++kt) {
            acc[0] = __builtin_amdgcn_mfma_f32_16x16x32_bf16(ah[kt], WR[0][kt], acc[0], 0, 0, 0);
            acc[1] = __builtin_amdgcn_mfma_f32_16x16x32_bf16(ah[kt], WR[1][kt], acc[1], 0, 0, 0);
            acc[2] = __builtin_amdgcn_mfma_f32_16x16x32_bf16(ah[kt], WR[2][kt], acc[2], 0, 0, 0);
            acc[3] = __builtin_amdgcn_mfma_f32_16x16x32_bf16(ah[kt], WR[3][kt], acc[3], 0, 0, 0);
            acc[4] = __builtin_amdgcn_mfma_f32_16x16x32_bf16(ah[kt], WR[4][kt], acc[4], 0, 0, 0);
            acc[5] = __builtin_amdgcn_mfma_f32_16x16x32_bf16(ah[kt], WR[5][kt], acc[5], 0, 0, 0);
        }
        // ---- pass B: o gates (16 MFMA, VGPR-hoisted lw) ----
        #pragma unroll
        for (int kt = 0; kt < 8; ++kt) {
            acc[6] = __builtin_amdgcn_mfma_f32_16x16x32_bf16(ah[kt], lw0[kt], acc[6], 0, 0, 0);
            acc[7] = __builtin_amdgcn_mfma_f32_16x16x32_bf16(ah[kt], lw1[kt], acc[7], 0, 0, 0);
        }

        // ---- single cell per lane: block bsel, row rsel ----
        // gates: i,j,f from pass A (chain hides under pass B drain), o last.
        float gi = (bsel ? acc[1][0] : acc[0][0]) + wx.x;   // x log2e
        float gj = (bsel ? acc[3][0] : acc[2][0]) + wx.y;   // x 2log2e
        float gf = (bsel ? acc[5][0] : acc[4][0]) + wx.z;   // forget_bias folded
        float si = RCPF(1.0f + EXP2(-gi));
        float tj = fmaf(-2.0f, RCPF(EXP2(gj) + 1.0f), 1.0f);
        float sf = RCPF(1.0f + EXP2(-gf));
        float c  = fmaf(cst0, sf, si * tj);
        cst0 = c;
        float th = fmaf(-2.0f, RCPF(EXP2(c * L2E2) + 1.0f), 1.0f);

        float go = (bsel ? acc[7][0] : acc[6][0]) + wx.w;   // first pass-B read
        float so = RCPF(1.0f + EXP2(-go));
        const short hv = (short)rne16(th * so);
        AH[p ^ 1][ktu][qau * 16 + mrow][ju]     = hv;   // primary copy
        AH[p ^ 1][ktu][qau * 16 + mrow + 8][ju] = hv;   // duplicate copy

        // prefetch next step's token (window-interior only)
        if (((t + 1) & 63) != 0)
            xq = tokw[(t + 1) & 63][rsel];

        __syncthreads();       // single barrier: plane p^1 now visible
    }

    // ---- final dense (h is bf16 in plane 0; 2 rows x 128 cols) ----
    // batch row r lives at M-row 4r (rows 0,4).
    for (int o = tid; o < BCR * NC; o += THREADS) {
        const int r = o >> 7;
        const int n = o & (NC - 1);
        float sum = bd[n];
        #pragma unroll 4
        for (int k = 0; k < U; ++k) {
            float hk = u2f(((unsigned)(unsigned short)
                            AH[0][k >> 5][((k >> 3) & 3) * 16 + 4 * r][k & 7]) << 16);
            sum = fmaf(hk, Wd[k * NC + n], sum);
        }
        out[(size_t)(r0 + r) * NC + n] = sum;
    }
}

// ================= fallback: round-5 streaming kernel (proven 7.6 ms) =========
__global__ __launch_bounds__(256)
void pack_kq(const float* __restrict__ Wh, uint4* __restrict__ Whb) {
    int idx = blockIdx.x * 256 + threadIdx.x;
    int kq  = idx >> 10;
    int c   = idx & 1023;
    const float* base = Wh + (size_t)(kq * 8) * GDIM + c;
    unsigned p0 = rne16(base[0 * GDIM]) | (rne16(base[1 * GDIM]) << 16);
    unsigned p1 = rne16(base[2 * GDIM]) | (rne16(base[3 * GDIM]) << 16);
    unsigned p2 = rne16(base[4 * GDIM]) | (rne16(base[5 * GDIM]) << 16);
    unsigned p3 = rne16(base[6 * GDIM]) | (rne16(base[7 * GDIM]) << 16);
    Whb[idx] = make_uint4(p0, p1, p2, p3);
}

__global__ __launch_bounds__(1024, 4)
void lstm_stream(const int* __restrict__ tokens, const float* __restrict__ Wx,
                 const uint4* __restrict__ Whb, const float* __restrict__ bias,
                 const float* __restrict__ Wd, const float* __restrict__ bd,
                 float* __restrict__ out)
{
    __shared__ float h32[2][U];
    __shared__ float G2[GDIM][2];
    __shared__ int   tok[2][SEQ];
    const int tid = threadIdx.x;
    const int r0  = blockIdx.x * 2;
    for (int i = tid; i < 2 * SEQ; i += 1024)
        ((int*)tok)[i] = tokens[r0 * SEQ + i];
    if (tid < 2 * U) ((float*)h32)[tid] = 0.0f;
    const float b_c = bias[tid];
    float c_state = 0.0f;
    const int ur = tid >> 8, uu = tid & 255;
    __syncthreads();
    const uint4* wp = Whb + tid;
    for (int t = 0; t < SEQ; ++t) {
        const int x0 = tok[0][t], x1 = tok[1][t];
        float a0e = Wx[x0 * GDIM + tid] + b_c;
        float a1e = Wx[x1 * GDIM + tid] + b_c;
        float a0o = 0.f, a1o = 0.f;
        #pragma unroll 4
        for (int kq = 0; kq < 32; ++kq) {
            float4 h0a = *(const float4*)&h32[0][kq * 8];
            float4 h0b = *(const float4*)&h32[0][kq * 8 + 4];
            float4 h1a = *(const float4*)&h32[1][kq * 8];
            float4 h1b = *(const float4*)&h32[1][kq * 8 + 4];
            uint4 wv2 = wp[kq << 10];
            float we0 = u2f(wv2.x << 16), wo0 = u2f(wv2.x & 0xffff0000u);
            float we1 = u2f(wv2.y << 16), wo1 = u2f(wv2.y & 0xffff0000u);
            float we2 = u2f(wv2.z << 16), wo2 = u2f(wv2.z & 0xffff0000u);
            float we3 = u2f(wv2.w << 16), wo3 = u2f(wv2.w & 0xffff0000u);
            a0e = fmaf(h0a.x, we0, a0e); a0o = fmaf(h0a.y, wo0, a0o);
            a1e = fmaf(h1a.x, we0, a1e); a1o = fmaf(h1a.y, wo0, a1o);
            a0e = fmaf(h0a.z, we1, a0e); a0o = fmaf(h0a.w, wo1, a0o);
            a1e = fmaf(h1a.z, we1, a1e); a1o = fmaf(h1a.w, wo1, a1o);
            a0e = fmaf(h0b.x, we2, a0e); a0o = fmaf(h0b.y, wo2, a0o);
            a1e = fmaf(h1b.x, we2, a1e); a1o = fmaf(h1b.y, wo2, a1o);
            a0e = fmaf(h0b.z, we3, a0e); a0o = fmaf(h0b.w, wo3, a0o);
            a1e = fmaf(h1b.z, we3, a1e); a1o = fmaf(h1b.w, wo3, a1o);
        }
        *(float2*)&G2[tid][0] = make_float2(a0e + a0o, a1e + a1o);
        __syncthreads();
        if (tid < 2 * U) {
            float gi = G2[uu][ur], gj = G2[U + uu][ur];
            float gf = G2[2 * U + uu][ur], go = G2[3 * U + uu][ur];
            c_state = c_state * sig_(gf + 1.0f) + sig_(gi) * tanh_(gj);
            h32[ur][uu] = tanh_(c_state) * sig_(go);
        }
        __syncthreads();
    }
    if (tid < 2 * NC) {
        const int r = tid >> 7, n = tid & (NC - 1);
        float sum = bd[n];
        #pragma unroll 4
        for (int k = 0; k < U; ++k)
            sum = fmaf(h32[r][k], Wd[k * NC + n], sum);
        out[(r0 + r) * NC + n] = sum;
    }
}

extern "C" void kernel_launch(void* const* d_in, const int* in_sizes, int n_in,
                              void* d_out, int out_size, void* d_ws, size_t ws_size,
                              hipStream_t stream) {
    const int*   tokens = (const int*)d_in[0];
    const float* Wx     = (const float*)d_in[1];
    const float* Wh     = (const float*)d_in[2];
    const float* bias   = (const float*)d_in[3];
    const float* Wd     = (const float*)d_in[4];
    const float* bd     = (const float*)d_in[5];
    float*       out    = (float*)d_out;

    if (ws_size >= (size_t)WS_NEED) {
        uint4*  Wp  = (uint4*)((char*)d_ws + WP_OFF);
        float4* Wxp = (float4*)((char*)d_ws + WXP_OFF);
        pack_wh<<<128, 256, 0, stream>>>(Wh, Wp);
        pack_wx<<<128, 256, 0, stream>>>(Wx, bias, Wxp);
        lstm_w256<<<512 / BCR, THREADS, 0, stream>>>(tokens, Wp, Wxp, Wd, bd, out);
    } else {
        uint4* Whb = (uint4*)d_ws;
        pack_kq<<<128, 256, 0, stream>>>(Wh, Whb);
        lstm_stream<<<256, 1024, 0, stream>>>(tokens, Wx, Whb, bias, Wd, bd, out);
    }
}